// Round 1
// baseline (202.720 us; speedup 1.0000x reference)
//
#include <hip/hip_runtime.h>

#define D 16
#define QPB 256       // queries per block == threads per block
#define TILE 128      // data points staged per LDS tile
#define NCHUNK 128    // data-dimension grid split

__device__ __forceinline__ float fast_exp2(float x) { return __builtin_amdgcn_exp2f(x); }
__device__ __forceinline__ float fast_log2(float x) { return __builtin_amdgcn_logf(x); }

#define LOG2E 1.4426950408889634f
#define LN2   0.6931471805599453f

// ---------------- sum of weights ----------------
__global__ void sumw_kernel(const float* __restrict__ w, int n, float* __restrict__ out) {
    float s = 0.f;
    for (int i = blockIdx.x * blockDim.x + threadIdx.x; i < n; i += gridDim.x * blockDim.x)
        s += w[i];
    #pragma unroll
    for (int off = 32; off > 0; off >>= 1) s += __shfl_down(s, off, 64);
    __shared__ float ls[4];
    int lane = threadIdx.x & 63, wv = threadIdx.x >> 6;
    if (lane == 0) ls[wv] = s;
    __syncthreads();
    if (threadIdx.x == 0) {
        float t = ls[0] + ls[1] + ls[2] + ls[3];
        atomicAdd(out, t);
    }
}

// ---------------- density partial sums ----------------
// acc[q] += sum_{n in chunk} exp2( L*(x_q . d_n) - 0.5*L*|d_n|^2 + log2 w_n )
// (the per-query term exp2(-0.5*L*|x_q|^2) is applied in the finalize kernel)
__global__ __launch_bounds__(QPB) void dens_kernel(
        const float* __restrict__ X, const float* __restrict__ data,
        const float* __restrict__ w, float* __restrict__ acc, int Q, int N) {
    __shared__ float4 sd[TILE * 4];   // TILE points x 16 floats
    __shared__ float  scn[TILE];      // per-point folded constant

    int q = blockIdx.x * QPB + threadIdx.x;
    bool qvalid = (q < Q);

    // query in registers, prescaled by log2(e)
    float x[D];
    #pragma unroll
    for (int k = 0; k < D; k++)
        x[k] = qvalid ? X[(size_t)q * D + k] * LOG2E : 0.f;

    int chunk = (N + NCHUNK - 1) / NCHUNK;
    int n0 = blockIdx.y * chunk;
    int n1 = min(n0 + chunk, N);

    float dens = 0.f;

    for (int t0 = n0; t0 < n1; t0 += TILE) {
        int cnt = min(TILE, n1 - t0);

        // cooperative stage: TILE*4 float4 loads, coalesced
        #pragma unroll
        for (int i = threadIdx.x; i < TILE * 4; i += QPB) {
            int pt = i >> 2;
            float4 v = make_float4(0.f, 0.f, 0.f, 0.f);
            if (pt < cnt)
                v = ((const float4*)data)[(size_t)(t0 + pt) * 4 + (i & 3)];
            sd[i] = v;
        }
        __syncthreads();

        // per-point constant: -0.5*L*|d|^2 + log2(w)
        if (threadIdx.x < TILE) {
            int j = threadIdx.x;
            float cn;
            if (j < cnt) {
                float dd = 0.f;
                #pragma unroll
                for (int r = 0; r < 4; r++) {
                    float4 v = sd[j * 4 + r];
                    dd += v.x * v.x + v.y * v.y + v.z * v.z + v.w * v.w;
                }
                cn = -0.5f * LOG2E * dd + fast_log2(w[t0 + j]);
            } else {
                cn = -1e30f;   // exp2 -> 0 for out-of-range slots
            }
            scn[j] = cn;
        }
        __syncthreads();

        // main loop: LDS broadcast reads, 16 FMA + exp2 + add per point
        for (int j = 0; j < TILE; j++) {
            float t = scn[j];
            #pragma unroll
            for (int r = 0; r < 4; r++) {
                float4 v = sd[j * 4 + r];
                t = fmaf(x[4 * r + 0], v.x, t);
                t = fmaf(x[4 * r + 1], v.y, t);
                t = fmaf(x[4 * r + 2], v.z, t);
                t = fmaf(x[4 * r + 3], v.w, t);
            }
            dens += fast_exp2(t);
        }
        __syncthreads();
    }

    if (qvalid) atomicAdd(&acc[q], dens);
}

// ---------------- finalize: log density ----------------
__global__ void fin_kernel(const float* __restrict__ X, const float* __restrict__ acc,
                           const float* __restrict__ sumw, float* __restrict__ out, int Q) {
    int q = blockIdx.x * blockDim.x + threadIdx.x;
    if (q >= Q) return;
    float xx = 0.f;
    #pragma unroll
    for (int k = 0; k < D; k++) {
        float v = X[(size_t)q * D + k];
        xx += v * v;
    }
    float aq = -0.5f * LOG2E * xx;                  // log2 of per-query factor
    const float ln_norm = -8.f * 1.8378770664093453f;  // ln((2*pi)^-8)
    float ld = LN2 * (aq + fast_log2(acc[q]) - fast_log2(sumw[0])) + ln_norm;
    out[q] = ld;
}

extern "C" void kernel_launch(void* const* d_in, const int* in_sizes, int n_in,
                              void* d_out, int out_size, void* d_ws, size_t ws_size,
                              hipStream_t stream) {
    const float* X    = (const float*)d_in[0];
    const float* data = (const float*)d_in[1];
    const float* w    = (const float*)d_in[2];
    float* out = (float*)d_out;
    int Q = in_sizes[0] / D;
    int N = in_sizes[1] / D;

    float* sumw = (float*)d_ws;       // ws[0]
    float* acc  = sumw + 1;           // ws[1 .. Q]

    hipMemsetAsync(d_ws, 0, (size_t)(1 + Q) * sizeof(float), stream);

    sumw_kernel<<<64, 256, 0, stream>>>(w, N, sumw);

    dim3 grid((Q + QPB - 1) / QPB, NCHUNK);
    dens_kernel<<<grid, QPB, 0, stream>>>(X, data, w, acc, Q, N);

    fin_kernel<<<(Q + 255) / 256, 256, 0, stream>>>(X, acc, sumw, out, Q);
}